// Round 4
// baseline (12953.506 us; speedup 1.0000x reference)
//
#include <hip/hip_runtime.h>
#include <hip/hip_bf16.h>

#define TT 512
#define BB 128
#define HH 512
#define NGROUP 8          // batch groups, 16 rows each
#define NSLICE 8          // col-slice blocks per group (16 cols * 4 waves each)
#define ALPHA 0.1f
#define NOISE_S 0.02f

typedef __attribute__((ext_vector_type(8))) short short8;
typedef __attribute__((ext_vector_type(8))) _Float16 half8;
typedef __attribute__((ext_vector_type(4))) float f32x4;

// ---- workspace layout (bytes) ----
#define WPACK_CH 132096                       // 16B chunks of packed weights
#define PUB1_B (WPACK_CH * 16)                // tanh1 pub: [NGROUP][16][64][8] fp16
#define PUB2_B (PUB1_B + NGROUP * 16384)      // tanh2 pub
#define FLAG_B (PUB2_B + NGROUP * 16384)      // flags: [NGROUP][2*TT] int

__device__ __forceinline__ unsigned short f2h(float f) {
  return __builtin_bit_cast(unsigned short, (_Float16)f);  // RNE
}

__device__ __forceinline__ float fast_tanh(float x) {
  float e = __builtin_amdgcn_exp2f(x * 2.8853900817779268f);
  return 1.0f - 2.0f * __builtin_amdgcn_rcpf(e + 1.0f);
}

__device__ __forceinline__ f32x4 mfma16(short8 a, short8 b, f32x4 c) {
  return __builtin_amdgcn_mfma_f32_16x16x32_f16(
      __builtin_bit_cast(half8, a), __builtin_bit_cast(half8, b), c, 0, 0, 0);
}

// ---------------------------------------------------------------------------
// Pack fp32 weights into fp16 MFMA B-fragment chunk order.
// chunk(kt, nt, lane)[i] = W[kt*32 + (lane>>4)*8 + i][nt*16 + (lane&15)]
//   WA = [wrec11; wrec12] (K=1024)  chunks [0, 65536)
//   WB = [wrec21; wrec22] (K=1024)  chunks [65536, 131072)
//   WO = wo padded to N=16 (K=512)  chunks [131072, 132096)
// ---------------------------------------------------------------------------
__global__ void pack_weights(const float* __restrict__ w11, const float* __restrict__ w12,
                             const float* __restrict__ w21, const float* __restrict__ w22,
                             const float* __restrict__ wo, unsigned short* __restrict__ dst) {
  int idx = blockIdx.x * 256 + threadIdx.x;
  if (idx < 131072) {
    int which = idx >> 16;
    int c0 = idx & 65535;
    int kt = c0 >> 11, rem = c0 & 2047;
    int nt = rem >> 6, lane = rem & 63;
    const float* wlo = which ? w21 : w11;   // k < 512  (multiplies tanh(h1))
    const float* whi = which ? w22 : w12;   // k >= 512 (multiplies tanh(h2))
    unsigned short* p = dst + (size_t)idx * 8;
    int n = nt * 16 + (lane & 15);
    int kb = kt * 32 + ((lane >> 4) & 3) * 8;
#pragma unroll
    for (int i = 0; i < 8; ++i) {
      int k = kb + i;
      float v = (k < HH) ? wlo[k * HH + n] : whi[(k - HH) * HH + n];
      p[i] = f2h(v);
    }
  } else if (idx < 132096) {
    int c0 = idx - 131072;
    int kt = c0 >> 6, lane = c0 & 63;
    unsigned short* p = dst + (size_t)131072 * 8 + (size_t)c0 * 8;
    int n = lane & 15;
    int kb = kt * 32 + ((lane >> 4) & 3) * 8;
#pragma unroll
    for (int i = 0; i < 8; ++i) {
      float v = (n < 3) ? wo[(kb + i) * 3 + n] : 0.0f;
      p[i] = f2h(v);
    }
  }
}

__global__ void zero_flags(int* __restrict__ f) {
  f[blockIdx.x * 1024 + threadIdx.x] = 0;   // 8 blocks x 1024 = NGROUP*2*TT
}

// ---------------------------------------------------------------------------
// Weight-stationary persistent RNN.
// Grid: 64 blocks = NSLICE(8) x NGROUP(8); group g = blockIdx&7 (same-XCD
// heuristic under round-robin dispatch; correctness is dispatch-independent).
// Block = 4 waves x 16 cols (nt = slice*4+w). Weights live in 256 VGPRs/wave.
// Per phase: MFMA from LDS tanh bufs -> h update -> publish fp16 tanh tile ->
// threadfence+atomicAdd (target 32 waves) -> relaxed spin -> stage to LDS.
// ---------------------------------------------------------------------------
__global__ __launch_bounds__(256, 1)
void rnn_main(const float* __restrict__ x, const float* __restrict__ wi_stim,
              const float* __restrict__ wi_ctx, const float* __restrict__ noise1,
              const float* __restrict__ noise2, char* __restrict__ ws,
              float* __restrict__ out) {
  __shared__ __align__(16) unsigned short T1buf[16 * 512];  // tanh(h1) A-chunks
  __shared__ __align__(16) unsigned short T2buf[16 * 512];  // tanh(h2) A-chunks
  __shared__ __align__(16) unsigned short WOlds[16 * 512];  // wo B-chunks
  __shared__ float xstage[2][16][5];

  const int tid = threadIdx.x;
  const int w = tid >> 6, lane = tid & 63;
  const int c16 = lane & 15, kh = lane >> 4;
  const int g = blockIdx.x & (NGROUP - 1);
  const int slice = blockIdx.x >> 3;
  const int nt = slice * 4 + w;          // n-tile 0..31
  const int n0 = nt * 16;
  const int b0 = g * 16;
  const int lrow0 = kh * 4;

  const short8* __restrict__ WC = (const short8*)ws;
  unsigned short* __restrict__ pub1 = (unsigned short*)(ws + PUB1_B) + g * 8192;
  unsigned short* __restrict__ pub2 = (unsigned short*)(ws + PUB2_B) + g * 8192;
  int* __restrict__ flags = (int*)(ws + FLAG_B) + g * (2 * TT);

  // ---- init LDS ----
  short8 z = {0, 0, 0, 0, 0, 0, 0, 0};
  for (int i = tid; i < 1024; i += 256) {
    ((short8*)T1buf)[i] = z;             // tanh(0) = 0
    ((short8*)T2buf)[i] = z;
  }
  if (slice == 0) {
#pragma unroll
    for (int c = 0; c < 4; ++c) {
      int kt = w * 4 + c;
      short8 v = WC[131072 + kt * 64 + lane];
      *(short8*)&WOlds[kt * 512 + lane * 8] = v;
    }
  }
  if (tid < 80) {
    int b = tid / 5, c = tid % 5;
    xstage[0][b][c] = x[((size_t)(b0 + b) * TT + 0) * 5 + c];
  }

  // ---- weights to registers (stationary for all 512 steps) ----
  short8 wA[32], wB[32];
#pragma unroll
  for (int kt = 0; kt < 32; ++kt) wA[kt] = WC[kt * 2048 + nt * 64 + lane];
#pragma unroll
  for (int kt = 0; kt < 32; ++kt) wB[kt] = WC[65536 + kt * 2048 + nt * 64 + lane];

  float wis[3], wic[2];
#pragma unroll
  for (int c = 0; c < 3; ++c) wis[c] = wi_stim[c * HH + n0 + c16];
#pragma unroll
  for (int c = 0; c < 2; ++c) wic[c] = wi_ctx[c * HH + n0 + c16];

  float h1[4] = {0, 0, 0, 0}, h2[4] = {0, 0, 0, 0};

  // publish address components: value (row, col=n0+c16) -> chunk layout
  const int kt_p = nt >> 1;
  const int hi = (((nt & 1) * 16) + c16) >> 3;
  const int ci = c16 & 7;

  __syncthreads();

  for (int t = 0; t < TT; ++t) {
    const int buf = t & 1;

    // prefetch noise for both phases (consumed in epilogues)
    float n1v[4], n2v[4];
#pragma unroll
    for (int r = 0; r < 4; ++r) {
      size_t rowoff = ((size_t)t * BB + b0 + lrow0 + r) * HH + n0 + c16;
      n1v[r] = noise1[rowoff];
      n2v[r] = noise2[rowoff];
    }

    // ---------------- phase A: h1' = 0.9 h1 + 0.1(xs Wi1 + T1 W11 + T2 W12 + n1)
    f32x4 aA = {0, 0, 0, 0}, aB = {0, 0, 0, 0};
#pragma unroll
    for (int kt = 0; kt < 16; ++kt) {
      short8 a1 = *(const short8*)&T1buf[kt * 512 + lane * 8];
      aA = mfma16(a1, wA[kt], aA);
      short8 a2 = *(const short8*)&T2buf[kt * 512 + lane * 8];
      aB = mfma16(a2, wA[16 + kt], aB);
    }
    unsigned short tp[4];
#pragma unroll
    for (int r = 0; r < 4; ++r) {
      float pre = aA[r] + aB[r]
                + wis[0] * xstage[buf][lrow0 + r][0]
                + wis[1] * xstage[buf][lrow0 + r][1]
                + wis[2] * xstage[buf][lrow0 + r][2]
                + NOISE_S * n1v[r];
      float h = (1.0f - ALPHA) * h1[r] + ALPHA * pre;
      h1[r] = h;
      tp[r] = f2h(fast_tanh(h));
    }
#pragma unroll
    for (int r = 0; r < 4; ++r)
      pub1[kt_p * 512 + (lrow0 + r + hi * 16) * 8 + ci] = tp[r];
    __threadfence();                       // release own wave's publish
    if (lane == 0) atomicAdd(&flags[2 * t], 1);

    // ---------------- phase B (w22 half first: T2 is stable across the sync)
    f32x4 bA = {0, 0, 0, 0}, bB = {0, 0, 0, 0};
#pragma unroll
    for (int kt = 0; kt < 16; ++kt) {
      short8 a2 = *(const short8*)&T2buf[kt * 512 + lane * 8];
      bB = mfma16(a2, wB[16 + kt], bB);
    }
    while (__hip_atomic_load(&flags[2 * t], __ATOMIC_RELAXED,
                             __HIP_MEMORY_SCOPE_AGENT) < NSLICE * 4)
      __builtin_amdgcn_s_sleep(1);
    __threadfence();                       // acquire
#pragma unroll
    for (int c = 0; c < 4; ++c) {          // stage fresh T1' (16 KB across 4 waves)
      int kt = w * 4 + c;
      short8 v = *(const short8*)&pub1[kt * 512 + lane * 8];
      *(short8*)&T1buf[kt * 512 + lane * 8] = v;
    }
    __syncthreads();
#pragma unroll
    for (int kt = 0; kt < 16; ++kt) {      // w21 half with FRESH tanh(h1')
      short8 a1 = *(const short8*)&T1buf[kt * 512 + lane * 8];
      bA = mfma16(a1, wB[kt], bA);
    }
#pragma unroll
    for (int r = 0; r < 4; ++r) {
      float pre = bA[r] + bB[r]
                + wic[0] * xstage[buf][lrow0 + r][3]
                + wic[1] * xstage[buf][lrow0 + r][4]
                + NOISE_S * n2v[r];
      float h = (1.0f - ALPHA) * h2[r] + ALPHA * pre;
      h2[r] = h;
      tp[r] = f2h(fast_tanh(h));
    }
#pragma unroll
    for (int r = 0; r < 4; ++r)
      pub2[kt_p * 512 + (lrow0 + r + hi * 16) * 8 + ci] = tp[r];
    __threadfence();
    if (lane == 0) atomicAdd(&flags[2 * t + 1], 1);
    while (__hip_atomic_load(&flags[2 * t + 1], __ATOMIC_RELAXED,
                             __HIP_MEMORY_SCOPE_AGENT) < NSLICE * 4)
      __builtin_amdgcn_s_sleep(1);
    __threadfence();                       // acquire
#pragma unroll
    for (int c = 0; c < 4; ++c) {          // stage fresh T2'
      int kt = w * 4 + c;
      short8 v = *(const short8*)&pub2[kt * 512 + lane * 8];
      *(short8*)&T2buf[kt * 512 + lane * 8] = v;
    }
    if (t + 1 < TT && tid < 80) {
      int b = tid / 5, c = tid % 5;
      xstage[buf ^ 1][b][c] = x[((size_t)(b0 + b) * TT + (t + 1)) * 5 + c];
    }
    __syncthreads();

    // ---------------- output for step t: tanh(h2[t+1]) @ wo (slice 0, wave 0)
    if (slice == 0 && w == 0) {
      f32x4 ao = {0, 0, 0, 0};
#pragma unroll
      for (int kt = 0; kt < 16; ++kt) {
        short8 a2 = *(const short8*)&T2buf[kt * 512 + lane * 8];
        short8 bo = *(const short8*)&WOlds[kt * 512 + lane * 8];
        ao = mfma16(a2, bo, ao);
      }
      if (c16 < 3) {
#pragma unroll
        for (int r = 0; r < 4; ++r)
          out[((size_t)(b0 + lrow0 + r) * TT + t) * 3 + c16] = ao[r];
      }
    }
  }
}

extern "C" void kernel_launch(void* const* d_in, const int* in_sizes, int n_in,
                              void* d_out, int out_size, void* d_ws, size_t ws_size,
                              hipStream_t stream) {
  const float* x       = (const float*)d_in[0];
  const float* wi_stim = (const float*)d_in[1];
  const float* w11     = (const float*)d_in[2];
  const float* wi_ctx  = (const float*)d_in[3];
  const float* w22     = (const float*)d_in[4];
  const float* w12     = (const float*)d_in[5];
  const float* w21     = (const float*)d_in[6];
  const float* wo      = (const float*)d_in[7];
  const float* n1      = (const float*)d_in[8];
  const float* n2      = (const float*)d_in[9];
  char* ws = (char*)d_ws;                  // needs ~2.45 MB

  zero_flags<<<NGROUP, 1024, 0, stream>>>((int*)(ws + FLAG_B));
  pack_weights<<<516, 256, 0, stream>>>(w11, w12, w21, w22, wo,
                                        (unsigned short*)ws);
  rnn_main<<<NSLICE * NGROUP, 256, 0, stream>>>(x, wi_stim, wi_ctx, n1, n2, ws,
                                                (float*)d_out);
}

// Round 5
// 4468.139 us; speedup vs baseline: 2.8991x; 2.8991x over previous
//
#include <hip/hip_runtime.h>
#include <hip/hip_bf16.h>

#define TT 512
#define BB 128
#define HH 512
#define NGROUP 8          // batch groups, 16 rows each
#define NSLICE 8          // col-slice blocks per group (4 waves x 16 cols each)
#define ALPHA 0.1f
#define NOISE_S 0.02f

typedef __attribute__((ext_vector_type(8))) short short8;
typedef __attribute__((ext_vector_type(8))) _Float16 half8;
typedef __attribute__((ext_vector_type(4))) float f32x4;

// ---- workspace layout (bytes) ----
#define WPACK_CH 132096                       // 16B chunks of packed weights
#define PUB1_B (WPACK_CH * 16)                // tanh1 pub: [NGROUP][16][64][8] fp16
#define PUB2_B (PUB1_B + NGROUP * 16384)      // tanh2 pub
#define FLAG_B (PUB2_B + NGROUP * 16384)      // flags: [NGROUP][2*TT] int

__device__ __forceinline__ unsigned short f2h(float f) {
  return __builtin_bit_cast(unsigned short, (_Float16)f);  // RNE
}

__device__ __forceinline__ float fast_tanh(float x) {
  float e = __builtin_amdgcn_exp2f(x * 2.8853900817779268f);
  return 1.0f - 2.0f * __builtin_amdgcn_rcpf(e + 1.0f);
}

__device__ __forceinline__ f32x4 mfma16(short8 a, short8 b, f32x4 c) {
  return __builtin_amdgcn_mfma_f32_16x16x32_f16(
      __builtin_bit_cast(half8, a), __builtin_bit_cast(half8, b), c, 0, 0, 0);
}

// ---------------------------------------------------------------------------
// Pack fp32 weights into fp16 MFMA B-fragment chunk order.
// chunk(kt, nt, lane)[i] = W[kt*32 + (lane>>4)*8 + i][nt*16 + (lane&15)]
//   WA = [wrec11; wrec12] (K=1024)  chunks [0, 65536)
//   WB = [wrec21; wrec22] (K=1024)  chunks [65536, 131072)
//   WO = wo padded to N=16 (K=512)  chunks [131072, 132096)
// ---------------------------------------------------------------------------
__global__ void pack_weights(const float* __restrict__ w11, const float* __restrict__ w12,
                             const float* __restrict__ w21, const float* __restrict__ w22,
                             const float* __restrict__ wo, unsigned short* __restrict__ dst) {
  int idx = blockIdx.x * 256 + threadIdx.x;
  if (idx < 131072) {
    int which = idx >> 16;
    int c0 = idx & 65535;
    int kt = c0 >> 11, rem = c0 & 2047;
    int nt = rem >> 6, lane = rem & 63;
    const float* wlo = which ? w21 : w11;   // k < 512  (multiplies tanh(h1))
    const float* whi = which ? w22 : w12;   // k >= 512 (multiplies tanh(h2))
    unsigned short* p = dst + (size_t)idx * 8;
    int n = nt * 16 + (lane & 15);
    int kb = kt * 32 + ((lane >> 4) & 3) * 8;
#pragma unroll
    for (int i = 0; i < 8; ++i) {
      int k = kb + i;
      float v = (k < HH) ? wlo[k * HH + n] : whi[(k - HH) * HH + n];
      p[i] = f2h(v);
    }
  } else if (idx < 132096) {
    int c0 = idx - 131072;
    int kt = c0 >> 6, lane = c0 & 63;
    unsigned short* p = dst + (size_t)131072 * 8 + (size_t)c0 * 8;
    int n = lane & 15;
    int kb = kt * 32 + ((lane >> 4) & 3) * 8;
#pragma unroll
    for (int i = 0; i < 8; ++i) {
      float v = (n < 3) ? wo[(kb + i) * 3 + n] : 0.0f;
      p[i] = f2h(v);
    }
  }
}

__global__ void zero_flags(int* __restrict__ f) {
  f[blockIdx.x * 1024 + threadIdx.x] = 0;   // 8 x 1024 = NGROUP*2*TT
}

// ---------------------------------------------------------------------------
// Sliced persistent RNN, fence-free cross-block sync.
// Grid: 64 blocks = NSLICE(8) x NGROUP(8); group g = blockIdx&7 (round-robin
// puts a group's 8 blocks on one XCD; correctness is mapping-independent).
// Block = 4 waves x 16 cols (nt = slice*4+w); weights re-streamed from L2
// (256 KB/step/CU). Publishes go through IF$ via sc-bypass atomic stores;
// no __threadfence -> no L2 writebacks.
// ---------------------------------------------------------------------------
__global__ __launch_bounds__(256, 1)
void rnn_main(const float* __restrict__ x, const float* __restrict__ wi_stim,
              const float* __restrict__ wi_ctx, const float* __restrict__ noise1,
              const float* __restrict__ noise2, char* __restrict__ ws,
              float* __restrict__ out) {
  __shared__ __align__(16) unsigned short T1buf[16 * 512];  // tanh(h1) A-chunks
  __shared__ __align__(16) unsigned short T2buf[16 * 512];  // tanh(h2) A-chunks
  __shared__ __align__(16) unsigned short WOlds[16 * 512];  // wo B-chunks
  __shared__ float xstage[2][16][5];

  const int tid = threadIdx.x;
  const int w = tid >> 6, lane = tid & 63;
  const int c16 = lane & 15, kh = lane >> 4;
  const int g = blockIdx.x & (NGROUP - 1);
  const int slice = blockIdx.x >> 3;
  const int nt = slice * 4 + w;          // n-tile 0..31
  const int n0 = nt * 16;
  const int b0 = g * 16;
  const int lrow0 = kh * 4;

  const short8* __restrict__ WC = (const short8*)ws;
  unsigned short* __restrict__ pub1 = (unsigned short*)(ws + PUB1_B) + g * 8192;
  unsigned short* __restrict__ pub2 = (unsigned short*)(ws + PUB2_B) + g * 8192;
  int* __restrict__ flags = (int*)(ws + FLAG_B) + g * (2 * TT);

  // ---- init LDS ----
  short8 z = {0, 0, 0, 0, 0, 0, 0, 0};
  for (int i = tid; i < 1024; i += 256) {
    ((short8*)T1buf)[i] = z;             // tanh(0) = 0
    ((short8*)T2buf)[i] = z;
  }
  if (slice == 0) {
#pragma unroll
    for (int c = 0; c < 4; ++c) {
      int kt = w * 4 + c;
      short8 v = WC[131072 + kt * 64 + lane];
      *(short8*)&WOlds[kt * 512 + lane * 8] = v;
    }
  }
  if (tid < 80) {
    int b = tid / 5, c = tid % 5;
    xstage[0][b][c] = x[((size_t)(b0 + b) * TT + 0) * 5 + c];
  }

  float wis[3], wic[2];
#pragma unroll
  for (int c = 0; c < 3; ++c) wis[c] = wi_stim[c * HH + n0 + c16];
#pragma unroll
  for (int c = 0; c < 2; ++c) wic[c] = wi_ctx[c * HH + n0 + c16];

  float h1[4] = {0, 0, 0, 0}, h2[4] = {0, 0, 0, 0};

  // publish address components: value (row, col=n0+c16) -> A-chunk layout
  const int kt_p = nt >> 1;
  const int hi = (((nt & 1) * 16) + c16) >> 3;
  const int ci = c16 & 7;

  const short8* __restrict__ WAp = WC + nt * 64 + lane;           // wA[kt] at kt*2048
  const short8* __restrict__ WBp = WC + 65536 + nt * 64 + lane;   // wB[kt]

  __syncthreads();

  for (int t = 0; t < TT; ++t) {
    const int buf = t & 1;

    // prefetch noise for both phases (consumed in epilogues)
    float n1v[4], n2v[4];
#pragma unroll
    for (int r = 0; r < 4; ++r) {
      size_t rowoff = ((size_t)t * BB + b0 + lrow0 + r) * HH + n0 + c16;
      n1v[r] = noise1[rowoff];
      n2v[r] = noise2[rowoff];
    }

    // ---- phase A: h1' = 0.9 h1 + 0.1(xs Wi1 + T1 W11 + T2 W12 + n1) ----
    f32x4 aA = {0, 0, 0, 0}, aB = {0, 0, 0, 0};
#pragma unroll
    for (int kt = 0; kt < 16; ++kt) {
      short8 a1 = *(const short8*)&T1buf[kt * 512 + lane * 8];
      aA = mfma16(a1, WAp[kt * 2048], aA);
      short8 a2 = *(const short8*)&T2buf[kt * 512 + lane * 8];
      aB = mfma16(a2, WAp[(16 + kt) * 2048], aB);
    }
    unsigned short tp[4];
#pragma unroll
    for (int r = 0; r < 4; ++r) {
      float pre = aA[r] + aB[r]
                + wis[0] * xstage[buf][lrow0 + r][0]
                + wis[1] * xstage[buf][lrow0 + r][1]
                + wis[2] * xstage[buf][lrow0 + r][2]
                + NOISE_S * n1v[r];
      float h = (1.0f - ALPHA) * h1[r] + ALPHA * pre;
      h1[r] = h;
      tp[r] = f2h(fast_tanh(h));
    }
#pragma unroll
    for (int r = 0; r < 4; ++r)
      __hip_atomic_store(&pub1[kt_p * 512 + (lrow0 + r + hi * 16) * 8 + ci], tp[r],
                         __ATOMIC_RELAXED, __HIP_MEMORY_SCOPE_AGENT);
    asm volatile("s_waitcnt vmcnt(0)" ::: "memory");
    __syncthreads();                       // all waves' publishes at IF$
    if (tid == 0)
      __hip_atomic_fetch_add(&flags[2 * t], 1, __ATOMIC_RELAXED,
                             __HIP_MEMORY_SCOPE_AGENT);

    // ---- phase B, w22 half first: T2 is stable across the sync ----
    f32x4 bA = {0, 0, 0, 0}, bB = {0, 0, 0, 0};
#pragma unroll
    for (int kt = 0; kt < 16; ++kt) {
      short8 a2 = *(const short8*)&T2buf[kt * 512 + lane * 8];
      bB = mfma16(a2, WBp[(16 + kt) * 2048], bB);
    }
    while (__hip_atomic_load(&flags[2 * t], __ATOMIC_RELAXED,
                             __HIP_MEMORY_SCOPE_AGENT) < NSLICE)
      __builtin_amdgcn_s_sleep(1);
    __builtin_amdgcn_sched_barrier(0);
    asm volatile("" ::: "memory");
#pragma unroll
    for (int c = 0; c < 4; ++c) {          // stage fresh T1' (coherent loads)
      int kt = w * 4 + c;
      const unsigned long long* src =
          (const unsigned long long*)&pub1[kt * 512 + lane * 8];
      unsigned long long v0 = __hip_atomic_load(&src[0], __ATOMIC_RELAXED,
                                                __HIP_MEMORY_SCOPE_AGENT);
      unsigned long long v1 = __hip_atomic_load(&src[1], __ATOMIC_RELAXED,
                                                __HIP_MEMORY_SCOPE_AGENT);
      *(unsigned long long*)&T1buf[kt * 512 + lane * 8] = v0;
      *(unsigned long long*)&T1buf[kt * 512 + lane * 8 + 4] = v1;
    }
    __syncthreads();
#pragma unroll
    for (int kt = 0; kt < 16; ++kt) {      // w21 half with FRESH tanh(h1')
      short8 a1 = *(const short8*)&T1buf[kt * 512 + lane * 8];
      bA = mfma16(a1, WBp[kt * 2048], bA);
    }
#pragma unroll
    for (int r = 0; r < 4; ++r) {
      float pre = bA[r] + bB[r]
                + wic[0] * xstage[buf][lrow0 + r][3]
                + wic[1] * xstage[buf][lrow0 + r][4]
                + NOISE_S * n2v[r];
      float h = (1.0f - ALPHA) * h2[r] + ALPHA * pre;
      h2[r] = h;
      tp[r] = f2h(fast_tanh(h));
    }
#pragma unroll
    for (int r = 0; r < 4; ++r)
      __hip_atomic_store(&pub2[kt_p * 512 + (lrow0 + r + hi * 16) * 8 + ci], tp[r],
                         __ATOMIC_RELAXED, __HIP_MEMORY_SCOPE_AGENT);
    asm volatile("s_waitcnt vmcnt(0)" ::: "memory");
    __syncthreads();
    if (tid == 0)
      __hip_atomic_fetch_add(&flags[2 * t + 1], 1, __ATOMIC_RELAXED,
                             __HIP_MEMORY_SCOPE_AGENT);
    while (__hip_atomic_load(&flags[2 * t + 1], __ATOMIC_RELAXED,
                             __HIP_MEMORY_SCOPE_AGENT) < NSLICE)
      __builtin_amdgcn_s_sleep(1);
    __builtin_amdgcn_sched_barrier(0);
    asm volatile("" ::: "memory");
#pragma unroll
    for (int c = 0; c < 4; ++c) {          // stage fresh T2'
      int kt = w * 4 + c;
      const unsigned long long* src =
          (const unsigned long long*)&pub2[kt * 512 + lane * 8];
      unsigned long long v0 = __hip_atomic_load(&src[0], __ATOMIC_RELAXED,
                                                __HIP_MEMORY_SCOPE_AGENT);
      unsigned long long v1 = __hip_atomic_load(&src[1], __ATOMIC_RELAXED,
                                                __HIP_MEMORY_SCOPE_AGENT);
      *(unsigned long long*)&T2buf[kt * 512 + lane * 8] = v0;
      *(unsigned long long*)&T2buf[kt * 512 + lane * 8 + 4] = v1;
    }
    if (t + 1 < TT && tid < 80) {
      int b = tid / 5, c = tid % 5;
      xstage[buf ^ 1][b][c] = x[((size_t)(b0 + b) * TT + (t + 1)) * 5 + c];
    }
    __syncthreads();

    // ---- output for step t: tanh(h2') @ wo (slice 0, wave 0) ----
    if (slice == 0 && w == 0) {
      f32x4 ao = {0, 0, 0, 0};
#pragma unroll
      for (int kt = 0; kt < 16; ++kt) {
        short8 a2 = *(const short8*)&T2buf[kt * 512 + lane * 8];
        short8 bo = *(const short8*)&WOlds[kt * 512 + lane * 8];
        ao = mfma16(a2, bo, ao);
      }
      if (c16 < 3) {
#pragma unroll
        for (int r = 0; r < 4; ++r)
          out[((size_t)(b0 + lrow0 + r) * TT + t) * 3 + c16] = ao[r];
      }
    }
  }
}

extern "C" void kernel_launch(void* const* d_in, const int* in_sizes, int n_in,
                              void* d_out, int out_size, void* d_ws, size_t ws_size,
                              hipStream_t stream) {
  const float* x       = (const float*)d_in[0];
  const float* wi_stim = (const float*)d_in[1];
  const float* w11     = (const float*)d_in[2];
  const float* wi_ctx  = (const float*)d_in[3];
  const float* w22     = (const float*)d_in[4];
  const float* w12     = (const float*)d_in[5];
  const float* w21     = (const float*)d_in[6];
  const float* wo      = (const float*)d_in[7];
  const float* n1      = (const float*)d_in[8];
  const float* n2      = (const float*)d_in[9];
  char* ws = (char*)d_ws;                  // needs ~2.45 MB

  zero_flags<<<NGROUP, 1024, 0, stream>>>((int*)(ws + FLAG_B));
  pack_weights<<<516, 256, 0, stream>>>(w11, w12, w21, w22, wo,
                                        (unsigned short*)ws);
  rnn_main<<<NSLICE * NGROUP, 256, 0, stream>>>(x, wi_stim, wi_ctx, n1, n2, ws,
                                                (float*)d_out);
}

// Round 6
// 3744.888 us; speedup vs baseline: 3.4590x; 1.1931x over previous
//
#include <hip/hip_runtime.h>
#include <hip/hip_bf16.h>

#define TT 512
#define BB 128
#define HH 512
#define NGROUP 8          // batch groups, 16 rows each
#define NSLICE 8          // col-slice blocks per group (4 waves x 16 cols each)
#define ALPHA 0.1f
#define NOISE_S 0.02f

typedef __attribute__((ext_vector_type(8))) short short8;
typedef __attribute__((ext_vector_type(8))) _Float16 half8;
typedef __attribute__((ext_vector_type(4))) float f32x4;

// ---- workspace layout (bytes) ----
#define WPACK_CH 132096                       // 16B chunks of packed weights
#define PUB1_B (WPACK_CH * 16)                // tanh1 pub: [NGROUP][16][64][8] fp16
#define PUB2_B (PUB1_B + NGROUP * 16384)      // tanh2 pub
#define FLAG_B (PUB2_B + NGROUP * 16384)      // fl1[NGROUP][8], fl2[NGROUP][8] ints

__device__ __forceinline__ unsigned short f2h(float f) {
  return __builtin_bit_cast(unsigned short, (_Float16)f);  // RNE
}

__device__ __forceinline__ float fast_tanh(float x) {
  float e = __builtin_amdgcn_exp2f(x * 2.8853900817779268f);
  return 1.0f - 2.0f * __builtin_amdgcn_rcpf(e + 1.0f);
}

__device__ __forceinline__ f32x4 mfma16(short8 a, short8 b, f32x4 c) {
  return __builtin_amdgcn_mfma_f32_16x16x32_f16(
      __builtin_bit_cast(half8, a), __builtin_bit_cast(half8, b), c, 0, 0, 0);
}

// ---------------------------------------------------------------------------
// Pack fp32 weights into fp16 MFMA B-fragment chunk order.
// chunk(kt, nt, lane)[i] = W[kt*32 + (lane>>4)*8 + i][nt*16 + (lane&15)]
//   WA = [wrec11; wrec12] (K=1024)  chunks [0, 65536)
//   WB = [wrec21; wrec22] (K=1024)  chunks [65536, 131072)
//   WO = wo padded to N=16 (K=512)  chunks [131072, 132096)
// ---------------------------------------------------------------------------
__global__ void pack_weights(const float* __restrict__ w11, const float* __restrict__ w12,
                             const float* __restrict__ w21, const float* __restrict__ w22,
                             const float* __restrict__ wo, unsigned short* __restrict__ dst) {
  int idx = blockIdx.x * 256 + threadIdx.x;
  if (idx < 131072) {
    int which = idx >> 16;
    int c0 = idx & 65535;
    int kt = c0 >> 11, rem = c0 & 2047;
    int nt = rem >> 6, lane = rem & 63;
    const float* wlo = which ? w21 : w11;   // k < 512  (multiplies tanh(h1))
    const float* whi = which ? w22 : w12;   // k >= 512 (multiplies tanh(h2))
    unsigned short* p = dst + (size_t)idx * 8;
    int n = nt * 16 + (lane & 15);
    int kb = kt * 32 + ((lane >> 4) & 3) * 8;
#pragma unroll
    for (int i = 0; i < 8; ++i) {
      int k = kb + i;
      float v = (k < HH) ? wlo[k * HH + n] : whi[(k - HH) * HH + n];
      p[i] = f2h(v);
    }
  } else if (idx < 132096) {
    int c0 = idx - 131072;
    int kt = c0 >> 6, lane = c0 & 63;
    unsigned short* p = dst + (size_t)131072 * 8 + (size_t)c0 * 8;
    int n = lane & 15;
    int kb = kt * 32 + ((lane >> 4) & 3) * 8;
#pragma unroll
    for (int i = 0; i < 8; ++i) {
      float v = (n < 3) ? wo[(kb + i) * 3 + n] : 0.0f;
      p[i] = f2h(v);
    }
  }
}

// zero pub1+pub2+flags each launch (graph-replay safe)
__global__ void zero_ws(int* __restrict__ p, int n) {
  for (int i = blockIdx.x * 256 + threadIdx.x; i < n; i += gridDim.x * 256)
    p[i] = 0;
}

// ---------------------------------------------------------------------------
// Sliced persistent RNN; fence-free sync, per-slot flag stores (no RMW),
// late-poll schedule. Grid: 64 blocks = NSLICE(8) x NGROUP(8).
// Block = 4 waves x 16 cols (nt = slice*4+w); weights streamed from L2.
// Flags are monotonic step counters: fl1[s] = t+1 after slice s published
// tanh(h1') of step t; fl2[s] = t+1 after tanh(h2') of step t.
// Phase A of step t: W11xT1 MFMAs, poll fl2>=t, stage T2, W12xT2 MFMAs,
//   (rotating block computes out[t-1]), h1 update, publish pub1, fl1=t+1.
// Phase B: W22xT2 MFMAs, poll fl1>=t+1, stage T1', W21xT1', h2 update,
//   publish pub2, fl2=t+1.
// ---------------------------------------------------------------------------
__global__ __launch_bounds__(256, 1)
void rnn_main(const float* __restrict__ x, const float* __restrict__ wi_stim,
              const float* __restrict__ wi_ctx, const float* __restrict__ noise1,
              const float* __restrict__ noise2, char* __restrict__ ws,
              float* __restrict__ out) {
  __shared__ __align__(16) unsigned short T1buf[16 * 512];  // tanh(h1) A-chunks
  __shared__ __align__(16) unsigned short T2buf[16 * 512];  // tanh(h2) A-chunks
  __shared__ __align__(16) unsigned short WOlds[16 * 512];  // wo B-chunks
  __shared__ float xstage[2][16][5];

  const int tid = threadIdx.x;
  const int w = tid >> 6, lane = tid & 63;
  const int c16 = lane & 15, kh = lane >> 4;
  const int g = blockIdx.x & (NGROUP - 1);
  const int slice = blockIdx.x >> 3;
  const int nt = slice * 4 + w;          // n-tile 0..31
  const int n0 = nt * 16;
  const int b0 = g * 16;
  const int lrow0 = kh * 4;

  const short8* __restrict__ WC = (const short8*)ws;
  unsigned short* __restrict__ pub1 = (unsigned short*)(ws + PUB1_B) + g * 8192;
  unsigned short* __restrict__ pub2 = (unsigned short*)(ws + PUB2_B) + g * 8192;
  int* __restrict__ fl1 = (int*)(ws + FLAG_B) + g * 8;
  int* __restrict__ fl2 = (int*)(ws + FLAG_B) + NGROUP * 8 + g * 8;

  // ---- init LDS ----
  short8 z = {0, 0, 0, 0, 0, 0, 0, 0};
  for (int i = tid; i < 1024; i += 256) {
    ((short8*)T1buf)[i] = z;             // tanh(0) = 0
    ((short8*)T2buf)[i] = z;
  }
#pragma unroll
  for (int c = 0; c < 4; ++c) {          // all blocks: wo fragments to LDS
    int kt = w * 4 + c;
    short8 v = WC[131072 + kt * 64 + lane];
    *(short8*)&WOlds[kt * 512 + lane * 8] = v;
  }
  if (tid < 80) {
    int b = tid / 5, c = tid % 5;
    xstage[0][b][c] = x[((size_t)(b0 + b) * TT + 0) * 5 + c];
  }

  float wis[3], wic[2];
#pragma unroll
  for (int c = 0; c < 3; ++c) wis[c] = wi_stim[c * HH + n0 + c16];
#pragma unroll
  for (int c = 0; c < 2; ++c) wic[c] = wi_ctx[c * HH + n0 + c16];

  float h1[4] = {0, 0, 0, 0}, h2[4] = {0, 0, 0, 0};

  // publish address components: value (row, col=n0+c16) -> A-chunk layout
  const int kt_p = nt >> 1;
  const int hi = (((nt & 1) * 16) + c16) >> 3;
  const int ci = c16 & 7;

  const short8* __restrict__ WAp = WC + nt * 64 + lane;           // +kt*2048
  const short8* __restrict__ WBp = WC + 65536 + nt * 64 + lane;

  // wave-wide poll: all 8 slots >= target
  auto poll = [&](int* f, int target) {
    int v;
    do {
      v = (lane < 8) ? __hip_atomic_load(&f[lane], __ATOMIC_RELAXED,
                                         __HIP_MEMORY_SCOPE_AGENT)
                     : target;
    } while (!__all(v >= target));
    __builtin_amdgcn_sched_barrier(0);
    asm volatile("" ::: "memory");
  };

  __syncthreads();

  for (int t = 0; t < TT; ++t) {
    const int buf = t & 1;

    // ================= phase A =================
    float n1v[4];
#pragma unroll
    for (int r = 0; r < 4; ++r)
      n1v[r] = noise1[((size_t)t * BB + b0 + lrow0 + r) * HH + n0 + c16];

    f32x4 aA = {0, 0, 0, 0}, aB = {0, 0, 0, 0};
#pragma unroll
    for (int kt = 0; kt < 16; ++kt) {    // W11 x T1 (T1 already local)
      short8 a1 = *(const short8*)&T1buf[kt * 512 + lane * 8];
      aA = mfma16(a1, WAp[kt * 2048], aA);
    }
    poll(fl2, t);                        // wait tanh(h2[t]) published
#pragma unroll
    for (int c = 0; c < 4; ++c) {        // stage T2 (coherent loads)
      int kt = w * 4 + c;
      const unsigned long long* src =
          (const unsigned long long*)&pub2[kt * 512 + lane * 8];
      unsigned long long v0 = __hip_atomic_load(&src[0], __ATOMIC_RELAXED,
                                                __HIP_MEMORY_SCOPE_AGENT);
      unsigned long long v1 = __hip_atomic_load(&src[1], __ATOMIC_RELAXED,
                                                __HIP_MEMORY_SCOPE_AGENT);
      *(unsigned long long*)&T2buf[kt * 512 + lane * 8] = v0;
      *(unsigned long long*)&T2buf[kt * 512 + lane * 8 + 4] = v1;
    }
    __syncthreads();
#pragma unroll
    for (int kt = 0; kt < 16; ++kt) {    // W12 x T2
      short8 a2 = *(const short8*)&T2buf[kt * 512 + lane * 8];
      aB = mfma16(a2, WAp[(16 + kt) * 2048], aB);
    }

    // rotated output for step t-1: out[t-1] = tanh(h2[t]) @ wo = T2buf @ wo
    if (t > 0 && slice == ((t - 1) & 7) && w == 0) {
      f32x4 ao = {0, 0, 0, 0};
#pragma unroll
      for (int kt = 0; kt < 16; ++kt) {
        short8 a2 = *(const short8*)&T2buf[kt * 512 + lane * 8];
        short8 bo = *(const short8*)&WOlds[kt * 512 + lane * 8];
        ao = mfma16(a2, bo, ao);
      }
      if (c16 < 3) {
#pragma unroll
        for (int r = 0; r < 4; ++r)
          out[((size_t)(b0 + lrow0 + r) * TT + (t - 1)) * 3 + c16] = ao[r];
      }
    }

    unsigned short tp[4];
#pragma unroll
    for (int r = 0; r < 4; ++r) {
      float pre = aA[r] + aB[r]
                + wis[0] * xstage[buf][lrow0 + r][0]
                + wis[1] * xstage[buf][lrow0 + r][1]
                + wis[2] * xstage[buf][lrow0 + r][2]
                + NOISE_S * n1v[r];
      float h = (1.0f - ALPHA) * h1[r] + ALPHA * pre;
      h1[r] = h;
      tp[r] = f2h(fast_tanh(h));
    }
#pragma unroll
    for (int r = 0; r < 4; ++r)
      __hip_atomic_store(&pub1[kt_p * 512 + (lrow0 + r + hi * 16) * 8 + ci], tp[r],
                         __ATOMIC_RELAXED, __HIP_MEMORY_SCOPE_AGENT);
    asm volatile("s_waitcnt vmcnt(0)" ::: "memory");
    __syncthreads();                     // whole block's publish at IF$
    if (tid == 0)
      __hip_atomic_store(&fl1[slice], t + 1, __ATOMIC_RELAXED,
                         __HIP_MEMORY_SCOPE_AGENT);

    // ================= phase B =================
    float n2v[4];
#pragma unroll
    for (int r = 0; r < 4; ++r)
      n2v[r] = noise2[((size_t)t * BB + b0 + lrow0 + r) * HH + n0 + c16];

    f32x4 bA = {0, 0, 0, 0}, bB = {0, 0, 0, 0};
#pragma unroll
    for (int kt = 0; kt < 16; ++kt) {    // W22 x T2 (stable across sync)
      short8 a2 = *(const short8*)&T2buf[kt * 512 + lane * 8];
      bB = mfma16(a2, WBp[(16 + kt) * 2048], bB);
    }
    poll(fl1, t + 1);                    // wait tanh(h1[t+1]) published
#pragma unroll
    for (int c = 0; c < 4; ++c) {        // stage fresh T1'
      int kt = w * 4 + c;
      const unsigned long long* src =
          (const unsigned long long*)&pub1[kt * 512 + lane * 8];
      unsigned long long v0 = __hip_atomic_load(&src[0], __ATOMIC_RELAXED,
                                                __HIP_MEMORY_SCOPE_AGENT);
      unsigned long long v1 = __hip_atomic_load(&src[1], __ATOMIC_RELAXED,
                                                __HIP_MEMORY_SCOPE_AGENT);
      *(unsigned long long*)&T1buf[kt * 512 + lane * 8] = v0;
      *(unsigned long long*)&T1buf[kt * 512 + lane * 8 + 4] = v1;
    }
    if (t + 1 < TT && tid < 80) {
      int b = tid / 5, c = tid % 5;
      xstage[buf ^ 1][b][c] = x[((size_t)(b0 + b) * TT + (t + 1)) * 5 + c];
    }
    __syncthreads();
#pragma unroll
    for (int kt = 0; kt < 16; ++kt) {    // W21 x fresh tanh(h1')
      short8 a1 = *(const short8*)&T1buf[kt * 512 + lane * 8];
      bA = mfma16(a1, WBp[kt * 2048], bA);
    }
#pragma unroll
    for (int r = 0; r < 4; ++r) {
      float pre = bA[r] + bB[r]
                + wic[0] * xstage[buf][lrow0 + r][3]
                + wic[1] * xstage[buf][lrow0 + r][4]
                + NOISE_S * n2v[r];
      float h = (1.0f - ALPHA) * h2[r] + ALPHA * pre;
      h2[r] = h;
      tp[r] = f2h(fast_tanh(h));
    }
#pragma unroll
    for (int r = 0; r < 4; ++r)
      __hip_atomic_store(&pub2[kt_p * 512 + (lrow0 + r + hi * 16) * 8 + ci], tp[r],
                         __ATOMIC_RELAXED, __HIP_MEMORY_SCOPE_AGENT);
    asm volatile("s_waitcnt vmcnt(0)" ::: "memory");
    __syncthreads();
    if (tid == 0)
      __hip_atomic_store(&fl2[slice], t + 1, __ATOMIC_RELAXED,
                         __HIP_MEMORY_SCOPE_AGENT);
  }

  // ---- final output: out[TT-1] = tanh(h2[TT]) @ wo ----
  if (slice == ((TT - 1) & 7)) {
    poll(fl2, TT);
#pragma unroll
    for (int c = 0; c < 4; ++c) {
      int kt = w * 4 + c;
      const unsigned long long* src =
          (const unsigned long long*)&pub2[kt * 512 + lane * 8];
      unsigned long long v0 = __hip_atomic_load(&src[0], __ATOMIC_RELAXED,
                                                __HIP_MEMORY_SCOPE_AGENT);
      unsigned long long v1 = __hip_atomic_load(&src[1], __ATOMIC_RELAXED,
                                                __HIP_MEMORY_SCOPE_AGENT);
      *(unsigned long long*)&T2buf[kt * 512 + lane * 8] = v0;
      *(unsigned long long*)&T2buf[kt * 512 + lane * 8 + 4] = v1;
    }
    __syncthreads();
    if (w == 0) {
      f32x4 ao = {0, 0, 0, 0};
#pragma unroll
      for (int kt = 0; kt < 16; ++kt) {
        short8 a2 = *(const short8*)&T2buf[kt * 512 + lane * 8];
        short8 bo = *(const short8*)&WOlds[kt * 512 + lane * 8];
        ao = mfma16(a2, bo, ao);
      }
      if (c16 < 3) {
#pragma unroll
        for (int r = 0; r < 4; ++r)
          out[((size_t)(b0 + lrow0 + r) * TT + (TT - 1)) * 3 + c16] = ao[r];
      }
    }
  }
}

extern "C" void kernel_launch(void* const* d_in, const int* in_sizes, int n_in,
                              void* d_out, int out_size, void* d_ws, size_t ws_size,
                              hipStream_t stream) {
  const float* x       = (const float*)d_in[0];
  const float* wi_stim = (const float*)d_in[1];
  const float* w11     = (const float*)d_in[2];
  const float* wi_ctx  = (const float*)d_in[3];
  const float* w22     = (const float*)d_in[4];
  const float* w12     = (const float*)d_in[5];
  const float* w21     = (const float*)d_in[6];
  const float* wo      = (const float*)d_in[7];
  const float* n1      = (const float*)d_in[8];
  const float* n2      = (const float*)d_in[9];
  char* ws = (char*)d_ws;                  // needs ~2.4 MB

  int nz = (NGROUP * 16384 * 2 + 2 * NGROUP * 8 * 4) / 4;  // pub1+pub2+flags
  zero_ws<<<64, 256, 0, stream>>>((int*)(ws + PUB1_B), nz);
  pack_weights<<<516, 256, 0, stream>>>(w11, w12, w21, w22, wo,
                                        (unsigned short*)ws);
  rnn_main<<<NSLICE * NGROUP, 256, 0, stream>>>(x, wi_stim, wi_ctx, n1, n2, ws,
                                                (float*)d_out);
}

// Round 7
// 3578.060 us; speedup vs baseline: 3.6203x; 1.0466x over previous
//
#include <hip/hip_runtime.h>
#include <hip/hip_bf16.h>

#define TT 512
#define BB 128
#define HH 512
#define NGROUP 8          // batch groups, 16 rows each
#define NSLICE 8          // col-slice blocks per group (4 waves x 16 cols each)
#define ALPHA 0.1f
#define NOISE_S 0.02f

typedef __attribute__((ext_vector_type(8))) short short8;
typedef __attribute__((ext_vector_type(8))) _Float16 half8;
typedef __attribute__((ext_vector_type(4))) float f32x4;

// ---- workspace layout (bytes) ----
#define WPACK_CH 132096                       // 16B chunks of packed weights
#define PUB1_B (WPACK_CH * 16)                // tanh1 pub: [NGROUP][8192] u32 words
#define PUB2_B (PUB1_B + NGROUP * 32768)      // tanh2 pub: [NGROUP][8192] u32 words
// word = (step_tag << 16) | fp16_bits ; word idx = kt*512 + srow*8 + j

__device__ __forceinline__ unsigned short f2h(float f) {
  return __builtin_bit_cast(unsigned short, (_Float16)f);  // RNE
}

__device__ __forceinline__ float fast_tanh(float x) {
  float e = __builtin_amdgcn_exp2f(x * 2.8853900817779268f);
  return 1.0f - 2.0f * __builtin_amdgcn_rcpf(e + 1.0f);
}

__device__ __forceinline__ f32x4 mfma16(short8 a, short8 b, f32x4 c) {
  return __builtin_amdgcn_mfma_f32_16x16x32_f16(
      __builtin_bit_cast(half8, a), __builtin_bit_cast(half8, b), c, 0, 0, 0);
}

// ---------------------------------------------------------------------------
// Pack fp32 weights into fp16 MFMA B-fragment chunk order.
// chunk(kt, nt, lane)[i] = W[kt*32 + (lane>>4)*8 + i][nt*16 + (lane&15)]
//   WA = [wrec11; wrec12] (K=1024)  chunks [0, 65536)
//   WB = [wrec21; wrec22] (K=1024)  chunks [65536, 131072)
//   WO = wo padded to N=16 (K=512)  chunks [131072, 132096)
// ---------------------------------------------------------------------------
__global__ void pack_weights(const float* __restrict__ w11, const float* __restrict__ w12,
                             const float* __restrict__ w21, const float* __restrict__ w22,
                             const float* __restrict__ wo, unsigned short* __restrict__ dst) {
  int idx = blockIdx.x * 256 + threadIdx.x;
  if (idx < 131072) {
    int which = idx >> 16;
    int c0 = idx & 65535;
    int kt = c0 >> 11, rem = c0 & 2047;
    int nt = rem >> 6, lane = rem & 63;
    const float* wlo = which ? w21 : w11;   // k < 512  (multiplies tanh(h1))
    const float* whi = which ? w22 : w12;   // k >= 512 (multiplies tanh(h2))
    unsigned short* p = dst + (size_t)idx * 8;
    int n = nt * 16 + (lane & 15);
    int kb = kt * 32 + ((lane >> 4) & 3) * 8;
#pragma unroll
    for (int i = 0; i < 8; ++i) {
      int k = kb + i;
      float v = (k < HH) ? wlo[k * HH + n] : whi[(k - HH) * HH + n];
      p[i] = f2h(v);
    }
  } else if (idx < 132096) {
    int c0 = idx - 131072;
    int kt = c0 >> 6, lane = c0 & 63;
    unsigned short* p = dst + (size_t)131072 * 8 + (size_t)c0 * 8;
    int n = lane & 15;
    int kb = kt * 32 + ((lane >> 4) & 3) * 8;
#pragma unroll
    for (int i = 0; i < 8; ++i) {
      float v = (n < 3) ? wo[(kb + i) * 3 + n] : 0.0f;
      p[i] = f2h(v);
    }
  }
}

// zero pub1+pub2 each launch (tag 0 == initial state h=0, graph-replay safe)
__global__ void zero_ws(int* __restrict__ p, int n) {
  for (int i = blockIdx.x * 256 + threadIdx.x; i < n; i += gridDim.x * 256)
    p[i] = 0;
}

// ---------------------------------------------------------------------------
// Sliced persistent RNN; tag-in-data sync (no flags, no fences), VGPR-resident
// weights. Grid: 64 blocks = NSLICE(8) x NGROUP(8).
// Phase A (step t): W11xT1 -> poll/stage pub2(tag>=t) -> barrier -> W12xT2
//   (+rotated out[t-1]) -> h1 update -> publish pub1 tagged t+1.
// Phase B: W22xT2 -> poll/stage pub1(tag>=t+1) -> barrier -> W21xT1' ->
//   h2 update -> publish pub2 tagged t+1.
// WAR-safe: a producer reaches its next pub overwrite only after staging the
// full peer pub of the prior phase, which peers publish only after staging
// this pub -- tags never advance past a pending reader.
// ---------------------------------------------------------------------------
__global__ __launch_bounds__(256, 1)
void rnn_main(const float* __restrict__ x, const float* __restrict__ wi_stim,
              const float* __restrict__ wi_ctx, const float* __restrict__ noise1,
              const float* __restrict__ noise2, char* __restrict__ ws,
              float* __restrict__ out) {
  __shared__ __align__(16) unsigned short T1buf[16 * 512];  // tanh(h1) A-chunks
  __shared__ __align__(16) unsigned short T2buf[16 * 512];  // tanh(h2) A-chunks
  __shared__ __align__(16) unsigned short WOlds[16 * 512];  // wo B-chunks
  __shared__ float xstage[2][16][5];

  const int tid = threadIdx.x;
  const int w = tid >> 6, lane = tid & 63;
  const int c16 = lane & 15, kh = lane >> 4;
  const int g = blockIdx.x & (NGROUP - 1);
  const int slice = blockIdx.x >> 3;
  const int nt = slice * 4 + w;          // n-tile 0..31
  const int n0 = nt * 16;
  const int b0 = g * 16;
  const int lrow0 = kh * 4;

  const short8* __restrict__ WC = (const short8*)ws;
  unsigned* __restrict__ pub1 = (unsigned*)(ws + PUB1_B) + g * 8192;
  unsigned* __restrict__ pub2 = (unsigned*)(ws + PUB2_B) + g * 8192;

  // ---- init LDS ----
  short8 z = {0, 0, 0, 0, 0, 0, 0, 0};
  for (int i = tid; i < 1024; i += 256) {
    ((short8*)T1buf)[i] = z;             // tanh(0) = 0
    ((short8*)T2buf)[i] = z;
  }
#pragma unroll
  for (int c = 0; c < 4; ++c) {          // wo fragments to LDS (all blocks)
    int kt = w * 4 + c;
    short8 v = WC[131072 + kt * 64 + lane];
    *(short8*)&WOlds[kt * 512 + lane * 8] = v;
  }
  if (tid < 80) {
    int b = tid / 5, c = tid % 5;
    xstage[0][b][c] = x[((size_t)(b0 + b) * TT + 0) * 5 + c];
  }

  // ---- weights to VGPRs, pinned resident for all 512 steps ----
  short8 wA[32], wB[32];
#pragma unroll
  for (int kt = 0; kt < 32; ++kt) {
    wA[kt] = WC[kt * 2048 + nt * 64 + lane];
    wB[kt] = WC[65536 + kt * 2048 + nt * 64 + lane];
  }
#pragma unroll
  for (int kt = 0; kt < 32; ++kt) {
    asm volatile("" : "+v"(wA[kt]));
    asm volatile("" : "+v"(wB[kt]));
  }

  float wis[3], wic[2];
#pragma unroll
  for (int c = 0; c < 3; ++c) wis[c] = wi_stim[c * HH + n0 + c16];
#pragma unroll
  for (int c = 0; c < 2; ++c) wic[c] = wi_ctx[c * HH + n0 + c16];

  float h1[4] = {0, 0, 0, 0}, h2[4] = {0, 0, 0, 0};

  // publish address components: value (row=lrow0+r, col=n0+c16) -> chunk slot
  const int kt_p = nt >> 1;
  const int hi = (((nt & 1) * 16) + c16) >> 3;
  const int ci = c16 & 7;

  // poll own gather words until all tags >= exp, then unpack into LDS
  auto stage_poll = [&](const unsigned* pubw, unsigned short* Tbuf, unsigned exp) {
    unsigned long long v[4][4];
    bool ok;
    do {
      ok = true;
#pragma unroll
      for (int c = 0; c < 4; ++c) {
        const unsigned long long* src =
            (const unsigned long long*)(pubw + ((w * 4 + c) << 9)) + lane * 4;
#pragma unroll
        for (int j = 0; j < 4; ++j) {
          v[c][j] = __hip_atomic_load(&src[j], __ATOMIC_RELAXED,
                                      __HIP_MEMORY_SCOPE_AGENT);
          ok &= (((unsigned)(v[c][j] >> 16) & 0xffffu) >= exp);
          ok &= ((unsigned)(v[c][j] >> 48) >= exp);
        }
      }
    } while (!ok);
    __builtin_amdgcn_sched_barrier(0);
    asm volatile("" ::: "memory");
#pragma unroll
    for (int c = 0; c < 4; ++c) {
      unsigned long long u0 = (v[c][0] & 0xffffull)
                            | (((v[c][0] >> 32) & 0xffffull) << 16)
                            | ((v[c][1] & 0xffffull) << 32)
                            | (((v[c][1] >> 32) & 0xffffull) << 48);
      unsigned long long u1 = (v[c][2] & 0xffffull)
                            | (((v[c][2] >> 32) & 0xffffull) << 16)
                            | ((v[c][3] & 0xffffull) << 32)
                            | (((v[c][3] >> 32) & 0xffffull) << 48);
      *(unsigned long long*)&Tbuf[(w * 4 + c) * 512 + lane * 8] = u0;
      *(unsigned long long*)&Tbuf[(w * 4 + c) * 512 + lane * 8 + 4] = u1;
    }
  };

  __syncthreads();

  for (int t = 0; t < TT; ++t) {
    const int buf = t & 1;
    const unsigned tagA = (unsigned)(t + 1) << 16;

    // ================= phase A =================
    float n1v[4];
#pragma unroll
    for (int r = 0; r < 4; ++r)
      n1v[r] = noise1[((size_t)t * BB + b0 + lrow0 + r) * HH + n0 + c16];

    f32x4 aA = {0, 0, 0, 0}, aB = {0, 0, 0, 0};
#pragma unroll
    for (int kt = 0; kt < 16; ++kt) {    // W11 x T1 (local, stable)
      short8 a1 = *(const short8*)&T1buf[kt * 512 + lane * 8];
      aA = mfma16(a1, wA[kt], aA);
    }
    stage_poll(pub2, T2buf, (unsigned)t);  // tanh(h2[t])
    __syncthreads();
#pragma unroll
    for (int kt = 0; kt < 16; ++kt) {    // W12 x T2
      short8 a2 = *(const short8*)&T2buf[kt * 512 + lane * 8];
      aB = mfma16(a2, wA[16 + kt], aB);
    }

    // rotated output for step t-1: out[t-1] = tanh(h2[t]) @ wo
    if (t > 0 && slice == ((t - 1) & 7) && w == 0) {
      f32x4 ao = {0, 0, 0, 0};
#pragma unroll
      for (int kt = 0; kt < 16; ++kt) {
        short8 a2 = *(const short8*)&T2buf[kt * 512 + lane * 8];
        short8 bo = *(const short8*)&WOlds[kt * 512 + lane * 8];
        ao = mfma16(a2, bo, ao);
      }
      if (c16 < 3) {
#pragma unroll
        for (int r = 0; r < 4; ++r)
          out[((size_t)(b0 + lrow0 + r) * TT + (t - 1)) * 3 + c16] = ao[r];
      }
    }

    unsigned short tp[4];
#pragma unroll
    for (int r = 0; r < 4; ++r) {
      float pre = aA[r] + aB[r]
                + wis[0] * xstage[buf][lrow0 + r][0]
                + wis[1] * xstage[buf][lrow0 + r][1]
                + wis[2] * xstage[buf][lrow0 + r][2]
                + NOISE_S * n1v[r];
      float h = (1.0f - ALPHA) * h1[r] + ALPHA * pre;
      h1[r] = h;
      tp[r] = f2h(fast_tanh(h));
    }
#pragma unroll
    for (int r = 0; r < 4; ++r)
      __hip_atomic_store(&pub1[kt_p * 512 + (lrow0 + r + hi * 16) * 8 + ci],
                         tagA | tp[r], __ATOMIC_RELAXED, __HIP_MEMORY_SCOPE_AGENT);

    // ================= phase B =================
    float n2v[4];
#pragma unroll
    for (int r = 0; r < 4; ++r)
      n2v[r] = noise2[((size_t)t * BB + b0 + lrow0 + r) * HH + n0 + c16];

    f32x4 bA = {0, 0, 0, 0}, bB = {0, 0, 0, 0};
#pragma unroll
    for (int kt = 0; kt < 16; ++kt) {    // W22 x T2 (stable across sync)
      short8 a2 = *(const short8*)&T2buf[kt * 512 + lane * 8];
      bB = mfma16(a2, wB[16 + kt], bB);
    }
    stage_poll(pub1, T1buf, (unsigned)(t + 1));  // fresh tanh(h1[t+1])
    if (t + 1 < TT && tid < 80) {
      int b = tid / 5, c = tid % 5;
      xstage[buf ^ 1][b][c] = x[((size_t)(b0 + b) * TT + (t + 1)) * 5 + c];
    }
    __syncthreads();
#pragma unroll
    for (int kt = 0; kt < 16; ++kt) {    // W21 x fresh tanh(h1')
      short8 a1 = *(const short8*)&T1buf[kt * 512 + lane * 8];
      bA = mfma16(a1, wB[kt], bA);
    }
#pragma unroll
    for (int r = 0; r < 4; ++r) {
      float pre = bA[r] + bB[r]
                + wic[0] * xstage[buf][lrow0 + r][3]
                + wic[1] * xstage[buf][lrow0 + r][4]
                + NOISE_S * n2v[r];
      float h = (1.0f - ALPHA) * h2[r] + ALPHA * pre;
      h2[r] = h;
      tp[r] = f2h(fast_tanh(h));
    }
#pragma unroll
    for (int r = 0; r < 4; ++r)
      __hip_atomic_store(&pub2[kt_p * 512 + (lrow0 + r + hi * 16) * 8 + ci],
                         tagA | tp[r], __ATOMIC_RELAXED, __HIP_MEMORY_SCOPE_AGENT);
  }

  // ---- final output: out[TT-1] = tanh(h2[TT]) @ wo ----
  if (slice == ((TT - 1) & 7)) {
    stage_poll(pub2, T2buf, (unsigned)TT);
    __syncthreads();
    if (w == 0) {
      f32x4 ao = {0, 0, 0, 0};
#pragma unroll
      for (int kt = 0; kt < 16; ++kt) {
        short8 a2 = *(const short8*)&T2buf[kt * 512 + lane * 8];
        short8 bo = *(const short8*)&WOlds[kt * 512 + lane * 8];
        ao = mfma16(a2, bo, ao);
      }
      if (c16 < 3) {
#pragma unroll
        for (int r = 0; r < 4; ++r)
          out[((size_t)(b0 + lrow0 + r) * TT + (TT - 1)) * 3 + c16] = ao[r];
      }
    }
  }
}

extern "C" void kernel_launch(void* const* d_in, const int* in_sizes, int n_in,
                              void* d_out, int out_size, void* d_ws, size_t ws_size,
                              hipStream_t stream) {
  const float* x       = (const float*)d_in[0];
  const float* wi_stim = (const float*)d_in[1];
  const float* w11     = (const float*)d_in[2];
  const float* wi_ctx  = (const float*)d_in[3];
  const float* w22     = (const float*)d_in[4];
  const float* w12     = (const float*)d_in[5];
  const float* w21     = (const float*)d_in[6];
  const float* wo      = (const float*)d_in[7];
  const float* n1      = (const float*)d_in[8];
  const float* n2      = (const float*)d_in[9];
  char* ws = (char*)d_ws;                  // needs ~2.7 MB

  int nz = (NGROUP * 32768 * 2) / 4;       // pub1+pub2 words
  zero_ws<<<64, 256, 0, stream>>>((int*)(ws + PUB1_B), nz);
  pack_weights<<<516, 256, 0, stream>>>(w11, w12, w21, w22, wo,
                                        (unsigned short*)ws);
  rnn_main<<<NSLICE * NGROUP, 256, 0, stream>>>(x, wi_stim, wi_ctx, n1, n2, ws,
                                                (float*)d_out);
}